// Round 1
// baseline (1624.060 us; speedup 1.0000x reference)
//
#include <hip/hip_runtime.h>

// ChebConv (complex Chebyshev graph conv), MI355X / gfx950.
//
// Restructure: for each k, A_k = Lr_k@Xr - Li_k@Xi, B_k = Li_k@Xr + Lr_k@Xi
// computed edge-wise in ONE gather pass (reads Xr/Xi[col] once per edge).
// Then real = [A_0|A_1|A_2] @ W''(768x256) + bias, imag = [B...] @ W'' + bias,
// where W'' is exactly the `weight` input viewed flat [k*256+cin][cout].
//
// Pipeline per launch (graph-capture safe, d_ws rebuilt every call):
//   memset cnt -> k_hist -> k_scan (CSR row_ptr) -> k_fill (edge perm)
//   -> k_main: per block of 8 rows: phase1 gather into LDS A/B (48KB),
//              phase2 in-block [16x768]@[768x256] fp32 GEMM (no fp32 MFMA on CDNA4).

#define NN 50000
#define NE 1600000
#define C 256
#define KP1 3
#define ROWS 8   // rows per block; LDS = 2*8*768*4 = 48KB -> 3 blocks/CU

// ---------------- CSR build ----------------

__global__ __launch_bounds__(256) void k_hist(const int* __restrict__ rows,
                                              int* __restrict__ cnt) {
    int e = blockIdx.x * 256 + threadIdx.x;
    if (e < NE) atomicAdd(&cnt[rows[e]], 1);
}

__global__ __launch_bounds__(1024) void k_scan(const int* __restrict__ cnt,
                                               int* __restrict__ row_ptr,
                                               int* __restrict__ cursor) {
    __shared__ int part[1024];
    const int t = threadIdx.x;
    const int SEG = (NN + 1023) / 1024;  // 49
    int s0 = t * SEG; if (s0 > NN) s0 = NN;
    int s1 = s0 + SEG; if (s1 > NN) s1 = NN;
    int sum = 0;
    for (int i = s0; i < s1; ++i) sum += cnt[i];
    part[t] = sum;
    __syncthreads();
    // Hillis-Steele inclusive scan over 1024 partials
    for (int off = 1; off < 1024; off <<= 1) {
        int v = (t >= off) ? part[t - off] : 0;
        __syncthreads();
        part[t] += v;
        __syncthreads();
    }
    int run = part[t] - sum;  // exclusive prefix of this thread's segment
    for (int i = s0; i < s1; ++i) {
        int cv = cnt[i];
        row_ptr[i] = run;
        cursor[i] = run;
        run += cv;
    }
    if (t == 1023) row_ptr[NN] = run;  // == NE
}

__global__ __launch_bounds__(256) void k_fill(const int* __restrict__ rows,
                                              int* __restrict__ cursor,
                                              int* __restrict__ perm) {
    int e = blockIdx.x * 256 + threadIdx.x;
    if (e < NE) {
        int r = rows[e];
        int p = atomicAdd(&cursor[r], 1);
        perm[p] = e;
    }
}

// ---------------- fused gather + GEMM ----------------

__global__ __launch_bounds__(256, 3) void k_main(
    const float* __restrict__ Xr, const float* __restrict__ Xi,
    const float* __restrict__ Lr, const float* __restrict__ Li,
    const float* __restrict__ W,  const float* __restrict__ bias,
    const int* __restrict__ row_ptr, const int* __restrict__ perm,
    const int* __restrict__ cols, float* __restrict__ out)
{
    __shared__ float accA[ROWS][KP1 * C];  // real pre-GEMM accum
    __shared__ float accB[ROWS][KP1 * C];  // imag pre-GEMM accum

    const int row0 = blockIdx.x * ROWS;
    const int wave = threadIdx.x >> 6;
    const int lane = threadIdx.x & 63;

    // ---- phase 1: one wave per row; lane owns 4 channels (float4) ----
    for (int rr = wave; rr < ROWS; rr += 4) {
        const int r = row0 + rr;
        const int e0 = __builtin_amdgcn_readfirstlane(row_ptr[r]);
        const int e1 = __builtin_amdgcn_readfirstlane(row_ptr[r + 1]);

        float aA[KP1][4] = {};
        float aB[KP1][4] = {};

        int e = (e0 < e1) ? perm[e0] : 0;
        e = __builtin_amdgcn_readfirstlane(e);
        for (int i = e0; i < e1; ++i) {
            // scalar-path loads (uniform addresses) for edge metadata
            const int   c   = cols[e];
            const float vr0 = Lr[e], vr1 = Lr[NE + e], vr2 = Lr[2 * NE + e];
            const float vi0 = Li[e], vi1 = Li[NE + e], vi2 = Li[2 * NE + e];
            // prefetch next edge id (1-deep pipeline on the perm->cols chain)
            int en = (i + 1 < e1) ? perm[i + 1] : 0;
            en = __builtin_amdgcn_readfirstlane(en);

            const float4 xr = *reinterpret_cast<const float4*>(&Xr[(size_t)c * C + (lane << 2)]);
            const float4 xi = *reinterpret_cast<const float4*>(&Xi[(size_t)c * C + (lane << 2)]);
            const float xrv[4] = {xr.x, xr.y, xr.z, xr.w};
            const float xiv[4] = {xi.x, xi.y, xi.z, xi.w};
            const float vrk[KP1] = {vr0, vr1, vr2};
            const float vik[KP1] = {vi0, vi1, vi2};
#pragma unroll
            for (int k = 0; k < KP1; ++k) {
#pragma unroll
                for (int j = 0; j < 4; ++j) {
                    aA[k][j] = fmaf(vrk[k], xrv[j], fmaf(-vik[k], xiv[j], aA[k][j]));
                    aB[k][j] = fmaf(vik[k], xrv[j], fmaf( vrk[k], xiv[j], aB[k][j]));
                }
            }
            e = en;
        }

#pragma unroll
        for (int k = 0; k < KP1; ++k) {
            float4 va; va.x = aA[k][0]; va.y = aA[k][1]; va.z = aA[k][2]; va.w = aA[k][3];
            float4 vb; vb.x = aB[k][0]; vb.y = aB[k][1]; vb.z = aB[k][2]; vb.w = aB[k][3];
            *reinterpret_cast<float4*>(&accA[rr][k * C + (lane << 2)]) = va;
            *reinterpret_cast<float4*>(&accB[rr][k * C + (lane << 2)]) = vb;
        }
    }
    __syncthreads();

    // ---- phase 2: out[r][t] = sum_kc acc[r][kc] * W[kc][t] + bias[t] ----
    // thread t owns output channel t for all 8 rows (real + imag).
    // accA/accB reads are LDS broadcasts (same address across lanes) -> free.
    // W reads are coalesced and L2-resident (786KB < 4MB per-XCD L2).
    const int t = threadIdx.x;
    const float bs = bias[t];
    float racc[ROWS], iacc[ROWS];
#pragma unroll
    for (int r = 0; r < ROWS; ++r) { racc[r] = bs; iacc[r] = bs; }

    for (int kc = 0; kc < KP1 * C; kc += 4) {
        const float w0 = W[(size_t)(kc + 0) * C + t];
        const float w1 = W[(size_t)(kc + 1) * C + t];
        const float w2 = W[(size_t)(kc + 2) * C + t];
        const float w3 = W[(size_t)(kc + 3) * C + t];
#pragma unroll
        for (int r = 0; r < ROWS; ++r) {
            const float4 a = *reinterpret_cast<const float4*>(&accA[r][kc]);
            const float4 b = *reinterpret_cast<const float4*>(&accB[r][kc]);
            racc[r] = fmaf(a.x, w0, fmaf(a.y, w1, fmaf(a.z, w2, fmaf(a.w, w3, racc[r]))));
            iacc[r] = fmaf(b.x, w0, fmaf(b.y, w1, fmaf(b.z, w2, fmaf(b.w, w3, iacc[r]))));
        }
    }

#pragma unroll
    for (int r = 0; r < ROWS; ++r) {
        out[(size_t)(row0 + r) * C + t] = racc[r];                     // real
        out[(size_t)NN * C + (size_t)(row0 + r) * C + t] = iacc[r];    // imag
    }
}

// ---------------- launch ----------------

extern "C" void kernel_launch(void* const* d_in, const int* in_sizes, int n_in,
                              void* d_out, int out_size, void* d_ws, size_t ws_size,
                              hipStream_t stream) {
    const float* Xr   = (const float*)d_in[0];
    const float* Xi   = (const float*)d_in[1];
    const float* Lr   = (const float*)d_in[2];
    const float* Li   = (const float*)d_in[3];
    const float* W    = (const float*)d_in[4];
    const float* bias = (const float*)d_in[5];
    const int*   rows = (const int*)d_in[6];
    const int*   cols = (const int*)d_in[7];
    float* out = (float*)d_out;

    // ws layout (ints): cnt[NN] | row_ptr[NN+1] | cursor[NN] | perm[NE]  (~7 MB)
    int* ws      = (int*)d_ws;
    int* cnt     = ws;
    int* row_ptr = ws + NN;
    int* cursor  = ws + 2 * NN + 1;
    int* perm    = ws + 3 * NN + 1;

    hipMemsetAsync(cnt, 0, NN * sizeof(int), stream);
    k_hist<<<(NE + 255) / 256, 256, 0, stream>>>(rows, cnt);
    k_scan<<<1, 1024, 0, stream>>>(cnt, row_ptr, cursor);
    k_fill<<<(NE + 255) / 256, 256, 0, stream>>>(rows, cursor, perm);
    k_main<<<NN / ROWS, 256, 0, stream>>>(Xr, Xi, Lr, Li, W, bias,
                                          row_ptr, perm, cols, out);
}

// Round 2
// 1224.316 us; speedup vs baseline: 1.3265x; 1.3265x over previous
//
#include <hip/hip_runtime.h>

// ChebConv (complex Chebyshev graph conv), MI355X / gfx950.
//
// A_k = Lr_k@Xr - Li_k@Xi, B_k = Li_k@Xr + Lr_k@Xi computed edge-wise in one
// gather pass; then real = [A_0|A_1|A_2] @ W''(768x256) + bias (same for imag)
// where W'' is the `weight` input viewed flat [k*256+cin][cout].
//
// R2 changes vs R1:
//  - phase 2 uses bf16 MFMA (16x16x32) with hi/lo bf16 splitting of BOTH the
//    LDS accumulator and W (3 MFMA terms) -> ~fp32 precision at matrix rate.
//    W is pre-split once per launch (k_wconv) into fragment-native layout.
//  - phase 1 software-pipelined: 2 edges/iter, scalar (s_load) edge metadata
//    one pair ahead, X float4 loads one pair in flight; tail edges nullified
//    by zeroed coefficients (no divergent branches).
//  - LDS acc stride padded to 772 floats (conflict-minimal ds_read_b128).

#define NN 50000
#define NE 1600000
#define C 256
#define KP1 3
#define ROWS 8            // rows per block; M = 2*ROWS = 16 (real+imag stacked)
#define LSTR 772          // 768 + 4 pad floats
#define NKT 24            // 768 / 32 K-steps
#define WB_ELEMS (384 * 512)   // 196608 ushorts for hi (same again for lo)
#define WB_BYTE_OFF 7000064    // 16B-aligned, after the int scratch region

typedef __attribute__((ext_vector_type(8))) short bf16x8;
typedef __attribute__((ext_vector_type(4))) float f32x4;

__device__ __forceinline__ unsigned pack_hi2(float x, float y) {
    return (__float_as_uint(x) >> 16) | (__float_as_uint(y) & 0xffff0000u);
}
__device__ __forceinline__ float hi_part(float x) {
    return __uint_as_float(__float_as_uint(x) & 0xffff0000u);
}

// ---------------- CSR build ----------------

__global__ __launch_bounds__(256) void k_hist(const int* __restrict__ rows,
                                              int* __restrict__ cnt) {
    int e = blockIdx.x * 256 + threadIdx.x;
    if (e < NE) atomicAdd(&cnt[rows[e]], 1);
}

__global__ __launch_bounds__(1024) void k_scan(const int* __restrict__ cnt,
                                               int* __restrict__ row_ptr,
                                               int* __restrict__ cursor) {
    __shared__ int part[1024];
    const int t = threadIdx.x;
    const int SEG = (NN + 1023) / 1024;  // 49
    int s0 = t * SEG; if (s0 > NN) s0 = NN;
    int s1 = s0 + SEG; if (s1 > NN) s1 = NN;
    int sum = 0;
    for (int i = s0; i < s1; ++i) sum += cnt[i];
    part[t] = sum;
    __syncthreads();
    for (int off = 1; off < 1024; off <<= 1) {
        int v = (t >= off) ? part[t - off] : 0;
        __syncthreads();
        part[t] += v;
        __syncthreads();
    }
    int run = part[t] - sum;
    for (int i = s0; i < s1; ++i) {
        int cv = cnt[i];
        row_ptr[i] = run;
        cursor[i] = run;
        run += cv;
    }
    if (t == 1023) row_ptr[NN] = run;  // == NE
}

__global__ __launch_bounds__(256) void k_fill(const int* __restrict__ rows,
                                              int* __restrict__ cursor,
                                              int* __restrict__ perm) {
    int e = blockIdx.x * 256 + threadIdx.x;
    if (e < NE) {
        int r = rows[e];
        int p = atomicAdd(&cursor[r], 1);
        perm[p] = e;
    }
}

// ---------------- W -> bf16 hi/lo fragment-native layout ----------------
// frag id = kt*16 + nt ; element (lane, j) = W[kt*32 + (lane>>4)*8 + j][nt*16 + (lane&15)]
// stored at wb[frag*512 + lane*8 + j] (hi) and wb[WB_ELEMS + same] (lo).

__global__ __launch_bounds__(256) void k_wconv(const float* __restrict__ W,
                                               unsigned short* __restrict__ wb) {
    int t = blockIdx.x * 256 + threadIdx.x;           // 0..196607
    int frag = t >> 9, lane = (t >> 3) & 63, j = t & 7;
    int kt = frag >> 4, nt = frag & 15;
    int k = kt * 32 + (lane >> 4) * 8 + j;
    int n = nt * 16 + (lane & 15);
    float w = W[k * C + n];
    unsigned b = __float_as_uint(w);
    float rest = w - __uint_as_float(b & 0xffff0000u);
    wb[t] = (unsigned short)(b >> 16);
    wb[WB_ELEMS + t] = (unsigned short)(__float_as_uint(rest) >> 16);
}

// ---------------- fused gather + MFMA GEMM ----------------

__global__ __launch_bounds__(256, 3) void k_main(
    const float* __restrict__ Xr, const float* __restrict__ Xi,
    const float* __restrict__ Lr, const float* __restrict__ Li,
    const unsigned short* __restrict__ wb, const float* __restrict__ bias,
    const int* __restrict__ row_ptr, const int* __restrict__ perm,
    const int* __restrict__ cols, float* __restrict__ out)
{
    __shared__ float accAB[2 * ROWS][LSTR];  // rows 0-7 real, 8-15 imag

    const int row0 = blockIdx.x * ROWS;
    const int wave = threadIdx.x >> 6;
    const int lane = threadIdx.x & 63;
    const int ch = lane << 2;

    // ---- phase 1: one wave per row (2 rows/wave), pipelined edge gather ----
    for (int rr = wave; rr < ROWS; rr += 4) {
        const int r = row0 + rr;
        const int e0 = __builtin_amdgcn_readfirstlane(row_ptr[r]);
        const int e1 = __builtin_amdgcn_readfirstlane(row_ptr[r + 1]);
        const int cnt = e1 - e0;
        const int npair = (cnt + 1) >> 1;

        float aA[KP1][4] = {{0.f}};
        float aB[KP1][4] = {{0.f}};

        if (cnt > 0) {
            int cA[2], cB[2], cC[2];
            float vrA[2][KP1], viA[2][KP1];
            float vrB[2][KP1], viB[2][KP1];
            float vrC[2][KP1], viC[2][KP1];
            float4 xr0[2], xi0[2], xr1[2], xi1[2];

#define LOAD_META(P, cc, vr_, vi_) do { \
    _Pragma("unroll") \
    for (int s = 0; s < 2; ++s) { \
        const int off_ = (P) * 2 + s; \
        const int gi = e0 + ((off_ < cnt) ? off_ : (cnt - 1)); \
        const int e = __builtin_amdgcn_readfirstlane(perm[gi]); \
        const bool ok = off_ < cnt; \
        cc[s] = __builtin_amdgcn_readfirstlane(cols[e]); \
        vr_[s][0] = ok ? Lr[e] : 0.f; \
        vr_[s][1] = ok ? Lr[NE + e] : 0.f; \
        vr_[s][2] = ok ? Lr[2 * NE + e] : 0.f; \
        vi_[s][0] = ok ? Li[e] : 0.f; \
        vi_[s][1] = ok ? Li[NE + e] : 0.f; \
        vi_[s][2] = ok ? Li[2 * NE + e] : 0.f; \
    } \
} while (0)

#define ISSUE_X(cc, xr_, xi_) do { \
    _Pragma("unroll") \
    for (int s = 0; s < 2; ++s) { \
        const size_t b_ = (size_t)cc[s] * C + ch; \
        xr_[s] = *reinterpret_cast<const float4*>(&Xr[b_]); \
        xi_[s] = *reinterpret_cast<const float4*>(&Xi[b_]); \
    } \
} while (0)

#define FMA_PAIR(vr_, vi_, xr_, xi_) do { \
    _Pragma("unroll") \
    for (int s = 0; s < 2; ++s) { \
        const float xrv[4] = {xr_[s].x, xr_[s].y, xr_[s].z, xr_[s].w}; \
        const float xiv[4] = {xi_[s].x, xi_[s].y, xi_[s].z, xi_[s].w}; \
        _Pragma("unroll") \
        for (int k = 0; k < KP1; ++k) { \
            _Pragma("unroll") \
            for (int j = 0; j < 4; ++j) { \
                aA[k][j] = fmaf(vr_[s][k], xrv[j], fmaf(-vi_[s][k], xiv[j], aA[k][j])); \
                aB[k][j] = fmaf(vi_[s][k], xrv[j], fmaf( vr_[s][k], xiv[j], aB[k][j])); \
            } \
        } \
    } \
} while (0)

            LOAD_META(0, cA, vrA, viA);
            ISSUE_X(cA, xr0, xi0);
            if (npair > 1) {
                LOAD_META(1, cB, vrB, viB);
#pragma unroll 2
                for (int p = 0; p < npair - 1; ++p) {
                    ISSUE_X(cB, xr1, xi1);           // X for pair p+1 (meta aged 1 iter)
                    LOAD_META(p + 2, cC, vrC, viC);  // meta 2 ahead (clamped+nullified at tail)
                    FMA_PAIR(vrA, viA, xr0, xi0);    // consume pair p (waits only its loads)
#pragma unroll
                    for (int s = 0; s < 2; ++s) {
                        cA[s] = cB[s]; cB[s] = cC[s];
#pragma unroll
                        for (int k = 0; k < KP1; ++k) {
                            vrA[s][k] = vrB[s][k]; vrB[s][k] = vrC[s][k];
                            viA[s][k] = viB[s][k]; viB[s][k] = viC[s][k];
                        }
                        xr0[s] = xr1[s]; xi0[s] = xi1[s];
                    }
                }
            }
            FMA_PAIR(vrA, viA, xr0, xi0);            // last pair
#undef LOAD_META
#undef ISSUE_X
#undef FMA_PAIR
        }

#pragma unroll
        for (int k = 0; k < KP1; ++k) {
            float4 va = {aA[k][0], aA[k][1], aA[k][2], aA[k][3]};
            float4 vb = {aB[k][0], aB[k][1], aB[k][2], aB[k][3]};
            *reinterpret_cast<float4*>(&accAB[rr][k * C + ch]) = va;
            *reinterpret_cast<float4*>(&accAB[rr + ROWS][k * C + ch]) = vb;
        }
    }
    __syncthreads();

    // ---- phase 2: [16 x 768] @ [768 x 256] via bf16 MFMA, hi/lo split ----
    const int m16 = lane & 15;
    const int oct = lane >> 4;
    const unsigned short* __restrict__ wlo = wb + WB_ELEMS;
    f32x4 acc0 = {0.f, 0.f, 0.f, 0.f};
    f32x4 acc1 = acc0, acc2 = acc0, acc3 = acc0;
    const int loff = lane * 8;

#pragma unroll 2
    for (int kt = 0; kt < NKT; ++kt) {
        const float4 a0 = *reinterpret_cast<const float4*>(&accAB[m16][kt * 32 + oct * 8]);
        const float4 a1 = *reinterpret_cast<const float4*>(&accAB[m16][kt * 32 + oct * 8 + 4]);
        union U { unsigned u[4]; bf16x8 v; };
        U ah, al;
        ah.u[0] = pack_hi2(a0.x, a0.y); ah.u[1] = pack_hi2(a0.z, a0.w);
        ah.u[2] = pack_hi2(a1.x, a1.y); ah.u[3] = pack_hi2(a1.z, a1.w);
        al.u[0] = pack_hi2(a0.x - hi_part(a0.x), a0.y - hi_part(a0.y));
        al.u[1] = pack_hi2(a0.z - hi_part(a0.z), a0.w - hi_part(a0.w));
        al.u[2] = pack_hi2(a1.x - hi_part(a1.x), a1.y - hi_part(a1.y));
        al.u[3] = pack_hi2(a1.z - hi_part(a1.z), a1.w - hi_part(a1.w));

        const int fb = (kt * 16 + (wave << 2)) * 512 + loff;
#define DO_NT(Q, ACC) do { \
        const bf16x8 wh = *reinterpret_cast<const bf16x8*>(&wb[fb + (Q) * 512]); \
        const bf16x8 wl = *reinterpret_cast<const bf16x8*>(&wlo[fb + (Q) * 512]); \
        ACC = __builtin_amdgcn_mfma_f32_16x16x32_bf16(ah.v, wh, ACC, 0, 0, 0); \
        ACC = __builtin_amdgcn_mfma_f32_16x16x32_bf16(al.v, wh, ACC, 0, 0, 0); \
        ACC = __builtin_amdgcn_mfma_f32_16x16x32_bf16(ah.v, wl, ACC, 0, 0, 0); \
} while (0)
        DO_NT(0, acc0); DO_NT(1, acc1); DO_NT(2, acc2); DO_NT(3, acc3);
#undef DO_NT
    }

    // D layout (m89-verified): col = lane&15, row = (lane>>4)*4 + reg
#define EPI(Q, ACC) do { \
    const int col = ((wave << 2) + (Q)) * 16 + m16; \
    const float bs = bias[col]; \
    _Pragma("unroll") \
    for (int j = 0; j < 4; ++j) { \
        const int mr = oct * 4 + j; \
        const float v = ACC[j] + bs; \
        const size_t o = (mr < ROWS) \
            ? ((size_t)(row0 + mr) * C + col) \
            : ((size_t)NN * C + (size_t)(row0 + mr - ROWS) * C + col); \
        out[o] = v; \
    } \
} while (0)
    EPI(0, acc0); EPI(1, acc1); EPI(2, acc2); EPI(3, acc3);
#undef EPI
}

// ---------------- launch ----------------

extern "C" void kernel_launch(void* const* d_in, const int* in_sizes, int n_in,
                              void* d_out, int out_size, void* d_ws, size_t ws_size,
                              hipStream_t stream) {
    const float* Xr   = (const float*)d_in[0];
    const float* Xi   = (const float*)d_in[1];
    const float* Lr   = (const float*)d_in[2];
    const float* Li   = (const float*)d_in[3];
    const float* W    = (const float*)d_in[4];
    const float* bias = (const float*)d_in[5];
    const int*   rows = (const int*)d_in[6];
    const int*   cols = (const int*)d_in[7];
    float* out = (float*)d_out;

    // ws layout (ints): cnt[NN] | row_ptr[NN+1] | cursor[NN] | perm[NE]
    // then at byte WB_BYTE_OFF: Wb_hi (384KB) | Wb_lo (384KB)
    int* ws      = (int*)d_ws;
    int* cnt     = ws;
    int* row_ptr = ws + NN;
    int* cursor  = ws + 2 * NN + 1;
    int* perm    = ws + 3 * NN + 1;
    unsigned short* wbp = (unsigned short*)((char*)d_ws + WB_BYTE_OFF);

    hipMemsetAsync(cnt, 0, NN * sizeof(int), stream);
    k_hist<<<(NE + 255) / 256, 256, 0, stream>>>(rows, cnt);
    k_scan<<<1, 1024, 0, stream>>>(cnt, row_ptr, cursor);
    k_fill<<<(NE + 255) / 256, 256, 0, stream>>>(rows, cursor, perm);
    k_wconv<<<(WB_ELEMS + 255) / 256, 256, 0, stream>>>(W, wbp);
    k_main<<<NN / ROWS, 256, 0, stream>>>(Xr, Xi, Lr, Li, wbp, bias,
                                          row_ptr, perm, cols, out);
}

// Round 3
// 937.686 us; speedup vs baseline: 1.7320x; 1.3057x over previous
//
#include <hip/hip_runtime.h>

// ChebConv (complex Chebyshev graph conv), MI355X / gfx950.
//
// A_k = Lr_k@Xr - Li_k@Xi, B_k = Li_k@Xr + Lr_k@Xi edge-wise in one gather
// pass; then real = [A_0|A_1|A_2] @ W''(768x256) + bias (same for imag) via
// bf16 MFMA with hi/lo split (3 terms ~ fp32 precision at matrix rate).
//
// R3 changes vs R2 (k_main was latency-bound: VALU 20%, MFMA 6%, HBM 40%):
//  - k_fill packs per-edge meta {col, vr0..2, vi0..2} as a 32B struct at the
//    CSR position -> k_main meta reads are wave-uniform SEQUENTIAL (s_load),
//    killing 6 scattered 4B L-loads/edge (~0.6GB HBM line waste) and the
//    perm->cols dependent chain.
//  - k_main: 512 thr / 8 waves, 1 row per wave, per-edge 4-slot software
//    pipeline (3 edges of X in flight), __launch_bounds__(512,4) -> 16
//    waves/CU (was 10.4).
//  - LDS XOR swizzle (cf ^= (row&7)<<2, stride 768) instead of +4 padding ->
//    minimal-aliasing ds_read_b128 / write_b128 both phases.

#define NN 50000
#define NE 1600000
#define C 256
#define KP1 3
#define ROWS 8                 // rows per block; M = 16 (real+imag stacked)
#define NKT 24                 // 768 / 32 K-steps
#define WB_ELEMS (384 * 512)   // 196608 ushorts hi (same again lo)

// ws layout (bytes):
//   0:            cnt[NN] ints
//   200000:       row_ptr[NN+1] ints
//   400004:       cursor[NN] ints
//   600064:       ed[NE] EdgeMeta (32B each) = 51,200,000 B
//   51800064:     wb hi/lo bf16 fragments (2 * 393216 B)
#define ED_BYTE_OFF 600064
#define WB_BYTE_OFF 51800064

typedef __attribute__((ext_vector_type(8))) short bf16x8;
typedef __attribute__((ext_vector_type(4))) float f32x4;

__device__ __forceinline__ unsigned pack_hi2(float x, float y) {
    return (__float_as_uint(x) >> 16) | (__float_as_uint(y) & 0xffff0000u);
}
__device__ __forceinline__ float hi_part(float x) {
    return __uint_as_float(__float_as_uint(x) & 0xffff0000u);
}

// ---------------- CSR build ----------------

__global__ __launch_bounds__(256) void k_hist(const int* __restrict__ rows,
                                              int* __restrict__ cnt) {
    int e = blockIdx.x * 256 + threadIdx.x;
    if (e < NE) atomicAdd(&cnt[rows[e]], 1);
}

__global__ __launch_bounds__(1024) void k_scan(const int* __restrict__ cnt,
                                               int* __restrict__ row_ptr,
                                               int* __restrict__ cursor) {
    __shared__ int part[1024];
    const int t = threadIdx.x;
    const int SEG = (NN + 1023) / 1024;  // 49
    int s0 = t * SEG; if (s0 > NN) s0 = NN;
    int s1 = s0 + SEG; if (s1 > NN) s1 = NN;
    int sum = 0;
    for (int i = s0; i < s1; ++i) sum += cnt[i];
    part[t] = sum;
    __syncthreads();
    for (int off = 1; off < 1024; off <<= 1) {
        int v = (t >= off) ? part[t - off] : 0;
        __syncthreads();
        part[t] += v;
        __syncthreads();
    }
    int run = part[t] - sum;
    for (int i = s0; i < s1; ++i) {
        int cv = cnt[i];
        row_ptr[i] = run;
        cursor[i] = run;
        run += cv;
    }
    if (t == 1023) row_ptr[NN] = run;  // == NE
}

// pack edge meta at CSR position: reads all coalesced (e = tid), write 32B scattered
__global__ __launch_bounds__(256) void k_fill(const int* __restrict__ rows,
                                              const int* __restrict__ cols,
                                              const float* __restrict__ Lr,
                                              const float* __restrict__ Li,
                                              int* __restrict__ cursor,
                                              float4* __restrict__ ed) {
    int e = blockIdx.x * 256 + threadIdx.x;
    if (e < NE) {
        int r = rows[e];
        int p = atomicAdd(&cursor[r], 1);
        float4 m0 = {__int_as_float(cols[e]), Lr[e], Lr[NE + e], Lr[2 * NE + e]};
        float4 m1 = {Li[e], Li[NE + e], Li[2 * NE + e], 0.f};
        ed[2 * p] = m0;
        ed[2 * p + 1] = m1;
    }
}

// ---------------- W -> bf16 hi/lo fragment-native layout ----------------
// frag id = kt*16 + nt ; element (lane, j) = W[kt*32 + (lane>>4)*8 + j][nt*16 + (lane&15)]

__global__ __launch_bounds__(256) void k_wconv(const float* __restrict__ W,
                                               unsigned short* __restrict__ wb) {
    int t = blockIdx.x * 256 + threadIdx.x;           // 0..196607
    int frag = t >> 9, lane = (t >> 3) & 63, j = t & 7;
    int kt = frag >> 4, nt = frag & 15;
    int k = kt * 32 + (lane >> 4) * 8 + j;
    int n = nt * 16 + (lane & 15);
    float w = W[k * C + n];
    unsigned b = __float_as_uint(w);
    float rest = w - __uint_as_float(b & 0xffff0000u);
    wb[t] = (unsigned short)(b >> 16);
    wb[WB_ELEMS + t] = (unsigned short)(__float_as_uint(rest) >> 16);
}

// ---------------- fused gather + MFMA GEMM ----------------

__global__ __launch_bounds__(512, 4) void k_main(
    const float* __restrict__ Xr, const float* __restrict__ Xi,
    const float4* __restrict__ ed, const unsigned short* __restrict__ wb,
    const float* __restrict__ bias, const int* __restrict__ row_ptr,
    float* __restrict__ out)
{
    __shared__ float lds[16 * 768];   // rows 0-7 real, 8-15 imag, XOR-swizzled

    const int row0 = blockIdx.x * ROWS;
    const int wave = threadIdx.x >> 6;
    const int lane = threadIdx.x & 63;
    const int ch = lane << 2;

    // ---- phase 1: one wave per row; 4-slot per-edge pipeline, 3 X in flight ----
    const int r = row0 + wave;
    const int e0 = __builtin_amdgcn_readfirstlane(row_ptr[r]);
    const int e1 = __builtin_amdgcn_readfirstlane(row_ptr[r + 1]);
    const int cnt = e1 - e0;

    float aA[KP1][4] = {{0.f}};
    float aB[KP1][4] = {{0.f}};

    if (cnt > 0) {
        int   mc[4];
        float mvr[4][KP1], mvi[4][KP1];
        float4 xrS[4], xiS[4];

#define LOADM(P, J) do { \
    const int gi_ = e0 + (((P) < cnt) ? (P) : (cnt - 1)); \
    const float4 m0_ = ed[2 * gi_]; \
    const float4 m1_ = ed[2 * gi_ + 1]; \
    const bool ok_ = (P) < cnt; \
    mc[J] = __float_as_int(m0_.x); \
    mvr[J][0] = ok_ ? m0_.y : 0.f; \
    mvr[J][1] = ok_ ? m0_.z : 0.f; \
    mvr[J][2] = ok_ ? m0_.w : 0.f; \
    mvi[J][0] = ok_ ? m1_.x : 0.f; \
    mvi[J][1] = ok_ ? m1_.y : 0.f; \
    mvi[J][2] = ok_ ? m1_.z : 0.f; \
} while (0)

#define ISSUE_X(J) do { \
    const size_t b_ = (size_t)(unsigned)mc[J] * C + ch; \
    xrS[J] = *reinterpret_cast<const float4*>(&Xr[b_]); \
    xiS[J] = *reinterpret_cast<const float4*>(&Xi[b_]); \
} while (0)

#define FMAE(J) do { \
    const float xrv_[4] = {xrS[J].x, xrS[J].y, xrS[J].z, xrS[J].w}; \
    const float xiv_[4] = {xiS[J].x, xiS[J].y, xiS[J].z, xiS[J].w}; \
    _Pragma("unroll") \
    for (int k = 0; k < KP1; ++k) { \
        _Pragma("unroll") \
        for (int j = 0; j < 4; ++j) { \
            aA[k][j] = fmaf(mvr[J][k], xrv_[j], fmaf(-mvi[J][k], xiv_[j], aA[k][j])); \
            aB[k][j] = fmaf(mvi[J][k], xrv_[j], fmaf( mvr[J][k], xiv_[j], aB[k][j])); \
        } \
    } \
} while (0)

// body for edge P (slot J): consume, issue X for edge P+3 (slot (J+3)&3,
// meta loaded one body earlier), refill meta slot J with edge P+4.
#define BODY(P, J) do { \
    FMAE(J); \
    ISSUE_X((J + 3) & 3); \
    LOADM((P) + 4, J); \
} while (0)

        LOADM(0, 0); LOADM(1, 1); LOADM(2, 2); LOADM(3, 3);
        ISSUE_X(0); ISSUE_X(1); ISSUE_X(2);

        const int ne4 = (cnt + 3) & ~3;
        for (int p = 0; p < ne4; p += 4) {
            BODY(p + 0, 0);
            BODY(p + 1, 1);
            BODY(p + 2, 2);
            BODY(p + 3, 3);
        }
#undef LOADM
#undef ISSUE_X
#undef FMAE
#undef BODY
    }

    // LDS write, XOR-swizzled: phys col = cf ^ ((row&7)<<2)
    {
        const int xsw = (wave & 7) << 2;
#pragma unroll
        for (int k = 0; k < KP1; ++k) {
            const int cf = k * C + ch;
            float4 va = {aA[k][0], aA[k][1], aA[k][2], aA[k][3]};
            float4 vb = {aB[k][0], aB[k][1], aB[k][2], aB[k][3]};
            *reinterpret_cast<float4*>(&lds[wave * 768 + (cf ^ xsw)]) = va;
            *reinterpret_cast<float4*>(&lds[(wave + 8) * 768 + (cf ^ xsw)]) = vb;
        }
    }
    __syncthreads();

    // ---- phase 2: [16 x 768] @ [768 x 256] via bf16 MFMA hi/lo; 2 nt/wave ----
    const int m16 = lane & 15;
    const int oct = lane >> 4;
    const int swz = (m16 & 7) << 2;
    const unsigned short* __restrict__ wlo = wb + WB_ELEMS;
    f32x4 acc0 = {0.f, 0.f, 0.f, 0.f};
    f32x4 acc1 = acc0;
    const int loff = lane * 8;

#pragma unroll 2
    for (int kt = 0; kt < NKT; ++kt) {
        const int c0 = kt * 32 + oct * 8;
        const float4 a0 = *reinterpret_cast<const float4*>(&lds[m16 * 768 + (c0 ^ swz)]);
        const float4 a1 = *reinterpret_cast<const float4*>(&lds[m16 * 768 + ((c0 + 4) ^ swz)]);
        union U { unsigned u[4]; bf16x8 v; };
        U ah, al;
        ah.u[0] = pack_hi2(a0.x, a0.y); ah.u[1] = pack_hi2(a0.z, a0.w);
        ah.u[2] = pack_hi2(a1.x, a1.y); ah.u[3] = pack_hi2(a1.z, a1.w);
        al.u[0] = pack_hi2(a0.x - hi_part(a0.x), a0.y - hi_part(a0.y));
        al.u[1] = pack_hi2(a0.z - hi_part(a0.z), a0.w - hi_part(a0.w));
        al.u[2] = pack_hi2(a1.x - hi_part(a1.x), a1.y - hi_part(a1.y));
        al.u[3] = pack_hi2(a1.z - hi_part(a1.z), a1.w - hi_part(a1.w));

        const int fb = (kt * 16 + (wave << 1)) * 512 + loff;
#define DO_NT(Q, ACC) do { \
        const bf16x8 wh = *reinterpret_cast<const bf16x8*>(&wb[fb + (Q) * 512]); \
        const bf16x8 wl = *reinterpret_cast<const bf16x8*>(&wlo[fb + (Q) * 512]); \
        ACC = __builtin_amdgcn_mfma_f32_16x16x32_bf16(ah.v, wh, ACC, 0, 0, 0); \
        ACC = __builtin_amdgcn_mfma_f32_16x16x32_bf16(al.v, wh, ACC, 0, 0, 0); \
        ACC = __builtin_amdgcn_mfma_f32_16x16x32_bf16(ah.v, wl, ACC, 0, 0, 0); \
} while (0)
        DO_NT(0, acc0); DO_NT(1, acc1);
#undef DO_NT
    }

    // D layout: col = lane&15, row = (lane>>4)*4 + reg
#define EPI(Q, ACC) do { \
    const int col = ((wave << 1) + (Q)) * 16 + m16; \
    const float bs = bias[col]; \
    _Pragma("unroll") \
    for (int j = 0; j < 4; ++j) { \
        const int mr = oct * 4 + j; \
        const float v = ACC[j] + bs; \
        const size_t o = (mr < ROWS) \
            ? ((size_t)(row0 + mr) * C + col) \
            : ((size_t)NN * C + (size_t)(row0 + mr - ROWS) * C + col); \
        out[o] = v; \
    } \
} while (0)
    EPI(0, acc0); EPI(1, acc1);
#undef EPI
}

// ---------------- launch ----------------

extern "C" void kernel_launch(void* const* d_in, const int* in_sizes, int n_in,
                              void* d_out, int out_size, void* d_ws, size_t ws_size,
                              hipStream_t stream) {
    const float* Xr   = (const float*)d_in[0];
    const float* Xi   = (const float*)d_in[1];
    const float* Lr   = (const float*)d_in[2];
    const float* Li   = (const float*)d_in[3];
    const float* W    = (const float*)d_in[4];
    const float* bias = (const float*)d_in[5];
    const int*   rows = (const int*)d_in[6];
    const int*   cols = (const int*)d_in[7];
    float* out = (float*)d_out;

    int* ws      = (int*)d_ws;
    int* cnt     = ws;
    int* row_ptr = ws + NN;
    int* cursor  = ws + 2 * NN + 1;
    float4* ed   = (float4*)((char*)d_ws + ED_BYTE_OFF);
    unsigned short* wbp = (unsigned short*)((char*)d_ws + WB_BYTE_OFF);

    hipMemsetAsync(cnt, 0, NN * sizeof(int), stream);
    k_hist<<<(NE + 255) / 256, 256, 0, stream>>>(rows, cnt);
    k_scan<<<1, 1024, 0, stream>>>(cnt, row_ptr, cursor);
    k_fill<<<(NE + 255) / 256, 256, 0, stream>>>(rows, cols, Lr, Li, cursor, ed);
    k_wconv<<<(WB_ELEMS + 255) / 256, 256, 0, stream>>>(W, wbp);
    k_main<<<NN / ROWS, 512, 0, stream>>>(Xr, Xi, ed, wbp, bias, row_ptr, out);
}

// Round 5
// 898.389 us; speedup vs baseline: 1.8077x; 1.0437x over previous
//
#include <hip/hip_runtime.h>

// ChebConv (complex Chebyshev graph conv), MI355X / gfx950.
//
// A_k = Lr_k@Xr - Li_k@Xi, B_k = Li_k@Xr + Lr_k@Xi edge-wise in one gather
// pass; then real = [A|..] @ W''(768x256) + bias via bf16 MFMA hi/lo split.
//
// R5 == R4 resubmit (R4 hit GPUAcquisitionTimeout; never measured), with
// phase-2 unroll reduced 4->2 to stay safely under the 64-VGPR cap imposed
// by __launch_bounds__(1024,8).
//
// R4 changes vs R3 (k_main latency-bound: VALU 46%, MFMA 9%, occ 44%):
//  - k_main: 1024 thr / 16 waves; each wave owns HALF a row's edges
//    (register partials merged via an LDS RMW pass) -> 2 blocks/CU,
//    target 32 waves/CU. __launch_bounds__(1024,8) caps VGPR at 64.
//  - X pre-packed per launch (k_xconv) as interleaved bf16 (xi<<16|xr):
//    gather = ONE dwordx4 per edge (1KB/edge, was 2KB).
//  - edge meta 16B (col + 3 bf16 L-pairs), halving k_fill scatter traffic.
//  - fragment-aware LDS swizzle: word = m*768 + (col&~31) + ((oct^(m&3))<<3)
//    + (col&7) -> 8-words/bank minimum on BOTH p1 writes and p2 reads.

#define NN 50000
#define NE 1600000
#define C 256
#define KP1 3
#define ROWS 8
#define NKT 24
#define WB_ELEMS (384 * 512)

// ws byte offsets: cnt | row_ptr | cursor | ed(16B/edge) | wb(hi+lo) | xp
#define RP_OFF   200000
#define CUR_OFF  400016
#define ED_OFF   600064
#define WB_OFF   26200064
#define XP_OFF   26986496   // end 78,186,496 bytes

typedef __attribute__((ext_vector_type(8))) short bf16x8;
typedef __attribute__((ext_vector_type(4))) float f32x4;

__device__ __forceinline__ unsigned bf16rne(float f) {
    unsigned u = __float_as_uint(f);
    return (u + 0x7fffu + ((u >> 16) & 1u)) >> 16;
}
__device__ __forceinline__ unsigned pack_hi2(float x, float y) {
    return (__float_as_uint(x) >> 16) | (__float_as_uint(y) & 0xffff0000u);
}
__device__ __forceinline__ float hi_part(float x) {
    return __uint_as_float(__float_as_uint(x) & 0xffff0000u);
}
// minimal-bank-pressure LDS word address for element (m, col)
__device__ __forceinline__ int lds_addr(int m, int col) {
    return m * 768 + (col & ~31) + ((((col >> 3) & 3) ^ (m & 3)) << 3) + (col & 7);
}

// ---------------- CSR build ----------------

__global__ __launch_bounds__(256) void k_hist(const int* __restrict__ rows,
                                              int* __restrict__ cnt) {
    int e = blockIdx.x * 256 + threadIdx.x;
    atomicAdd(&cnt[rows[e]], 1);           // NE % 256 == 0
}

__global__ __launch_bounds__(1024) void k_scan(const int* __restrict__ cnt,
                                               int* __restrict__ row_ptr,
                                               int* __restrict__ cursor) {
    __shared__ int part[1024];
    const int t = threadIdx.x;
    const int SEG = (NN + 1023) / 1024;  // 49
    int s0 = t * SEG; if (s0 > NN) s0 = NN;
    int s1 = s0 + SEG; if (s1 > NN) s1 = NN;
    int sum = 0;
    for (int i = s0; i < s1; ++i) sum += cnt[i];
    part[t] = sum;
    __syncthreads();
    for (int off = 1; off < 1024; off <<= 1) {
        int v = (t >= off) ? part[t - off] : 0;
        __syncthreads();
        part[t] += v;
        __syncthreads();
    }
    int run = part[t] - sum;
    for (int i = s0; i < s1; ++i) {
        int cv = cnt[i];
        row_ptr[i] = run;
        cursor[i] = run;
        run += cv;
    }
    if (t == 1023) row_ptr[NN] = run;  // == NE
}

// pack 16B edge meta {col, 3 x (bf16 vi<<16 | bf16 vr)} at CSR position
__global__ __launch_bounds__(256) void k_fill(const int* __restrict__ rows,
                                              const int* __restrict__ cols,
                                              const float* __restrict__ Lr,
                                              const float* __restrict__ Li,
                                              int* __restrict__ cursor,
                                              float4* __restrict__ ed) {
    int e = blockIdx.x * 256 + threadIdx.x;
    int r = rows[e];
    int p = atomicAdd(&cursor[r], 1);
    float4 m;
    m.x = __int_as_float(cols[e]);
    m.y = __uint_as_float(bf16rne(Lr[e])          | (bf16rne(Li[e])          << 16));
    m.z = __uint_as_float(bf16rne(Lr[NE + e])     | (bf16rne(Li[NE + e])     << 16));
    m.w = __uint_as_float(bf16rne(Lr[2 * NE + e]) | (bf16rne(Li[2 * NE + e]) << 16));
    ed[p] = m;
}

// ---------------- X -> interleaved bf16 pairs ----------------

__global__ __launch_bounds__(256) void k_xconv(const float* __restrict__ Xr,
                                               const float* __restrict__ Xi,
                                               unsigned* __restrict__ xp) {
    int t = blockIdx.x * 256 + threadIdx.x;   // NN*C % 256 == 0
    xp[t] = bf16rne(Xr[t]) | (bf16rne(Xi[t]) << 16);
}

// ---------------- W -> bf16 hi/lo fragment-native layout ----------------
// frag id = kt*16 + nt ; element (lane, j) = W[kt*32 + (lane>>4)*8 + j][nt*16 + (lane&15)]

__global__ __launch_bounds__(256) void k_wconv(const float* __restrict__ W,
                                               unsigned short* __restrict__ wb) {
    int t = blockIdx.x * 256 + threadIdx.x;           // 0..196607
    int frag = t >> 9, lane = (t >> 3) & 63, j = t & 7;
    int kt = frag >> 4, nt = frag & 15;
    int k = kt * 32 + (lane >> 4) * 8 + j;
    int n = nt * 16 + (lane & 15);
    float w = W[k * C + n];
    unsigned b = __float_as_uint(w);
    float rest = w - __uint_as_float(b & 0xffff0000u);
    wb[t] = (unsigned short)(b >> 16);
    wb[WB_ELEMS + t] = bf16rne(rest);
}

// ---------------- fused gather + MFMA GEMM ----------------

__global__ __launch_bounds__(1024, 8) void k_main(
    const unsigned* __restrict__ xp, const float4* __restrict__ ed,
    const unsigned short* __restrict__ wb, const float* __restrict__ bias,
    const int* __restrict__ row_ptr, float* __restrict__ out)
{
    __shared__ float lds[16 * 768];   // rows 0-7 real, 8-15 imag, swizzled

    const int row0 = blockIdx.x * ROWS;
    const int wave = threadIdx.x >> 6;
    const int lane = threadIdx.x & 63;
    const int w8 = wave & 7;
    const int half = wave >> 3;

    // ---- phase 1: two waves per row (edge halves); 3-slot pipeline ----
    const int r = row0 + w8;
    const int e0 = __builtin_amdgcn_readfirstlane(row_ptr[r]);
    const int e1 = __builtin_amdgcn_readfirstlane(row_ptr[r + 1]);
    const int cnt = e1 - e0;
    const int h0 = (cnt + 1) >> 1;
    const int me0 = e0 + (half ? h0 : 0);
    const int mcnt = half ? (cnt - h0) : h0;

    float aA[KP1][4] = {{0.f}};
    float aB[KP1][4] = {{0.f}};

    if (mcnt > 0) {
        unsigned mm[3][4];   // [slot] = {col, Lpair0, Lpair1, Lpair2}
        unsigned xq[3][4];   // [slot] = 4 channels of (bf16 xi<<16 | bf16 xr)

#define LOADM(P, J) do { \
    const int gi_ = __builtin_amdgcn_readfirstlane( \
        me0 + (((P) < mcnt) ? (P) : (mcnt - 1))); \
    const float4 m_ = ed[gi_]; \
    const bool ok_ = (P) < mcnt; \
    mm[J][0] = (unsigned)__float_as_int(m_.x); \
    mm[J][1] = ok_ ? __float_as_uint(m_.y) : 0u; \
    mm[J][2] = ok_ ? __float_as_uint(m_.z) : 0u; \
    mm[J][3] = ok_ ? __float_as_uint(m_.w) : 0u; \
} while (0)

#define ISSUE_X(J) do { \
    const unsigned off_ = (mm[J][0] << 8) + (unsigned)(lane << 2); \
    const uint4 v_ = *reinterpret_cast<const uint4*>(&xp[off_]); \
    xq[J][0] = v_.x; xq[J][1] = v_.y; xq[J][2] = v_.z; xq[J][3] = v_.w; \
} while (0)

#define FMAE(J) do { \
    float vr_[KP1], vi_[KP1]; \
    _Pragma("unroll") \
    for (int k = 0; k < KP1; ++k) { \
        vr_[k] = __uint_as_float(mm[J][k + 1] << 16); \
        vi_[k] = __uint_as_float(mm[J][k + 1] & 0xffff0000u); \
    } \
    _Pragma("unroll") \
    for (int j = 0; j < 4; ++j) { \
        const float xr_ = __uint_as_float(xq[J][j] << 16); \
        const float xi_ = __uint_as_float(xq[J][j] & 0xffff0000u); \
        _Pragma("unroll") \
        for (int k = 0; k < KP1; ++k) { \
            aA[k][j] = fmaf(vr_[k], xr_, fmaf(-vi_[k], xi_, aA[k][j])); \
            aB[k][j] = fmaf(vi_[k], xr_, fmaf( vr_[k], xi_, aB[k][j])); \
        } \
    } \
} while (0)

        LOADM(0, 0); LOADM(1, 1); LOADM(2, 2);
        ISSUE_X(0); ISSUE_X(1);
        const int ne3 = ((mcnt + 2) / 3) * 3;
        for (int p = 0; p < ne3; p += 3) {
            FMAE(0); ISSUE_X(2); LOADM(p + 3, 0);
            FMAE(1); ISSUE_X(0); LOADM(p + 4, 1);
            FMAE(2); ISSUE_X(1); LOADM(p + 5, 2);
        }
#undef LOADM
#undef ISSUE_X
#undef FMAE
    }

    // ---- merge halves into LDS (swizzled), then barrier ----
    const int ch = lane << 2;
    if (half == 0) {
#pragma unroll
        for (int k = 0; k < KP1; ++k) {
            const int col = k * C + ch;
            float4 va = {aA[k][0], aA[k][1], aA[k][2], aA[k][3]};
            float4 vb = {aB[k][0], aB[k][1], aB[k][2], aB[k][3]};
            *reinterpret_cast<float4*>(&lds[lds_addr(w8, col)]) = va;
            *reinterpret_cast<float4*>(&lds[lds_addr(w8 + 8, col)]) = vb;
        }
    }
    __syncthreads();
    if (half == 1) {
#pragma unroll
        for (int k = 0; k < KP1; ++k) {
            const int col = k * C + ch;
            float4* pa = reinterpret_cast<float4*>(&lds[lds_addr(w8, col)]);
            float4* pb = reinterpret_cast<float4*>(&lds[lds_addr(w8 + 8, col)]);
            float4 va = *pa, vb = *pb;
            va.x += aA[k][0]; va.y += aA[k][1]; va.z += aA[k][2]; va.w += aA[k][3];
            vb.x += aB[k][0]; vb.y += aB[k][1]; vb.z += aB[k][2]; vb.w += aB[k][3];
            *pa = va; *pb = vb;
        }
    }
    __syncthreads();

    // ---- phase 2: [16 x 768] @ [768 x 256] bf16 MFMA hi/lo; 1 nt per wave ----
    const int m16 = lane & 15;
    const int oct = lane >> 4;
    const int nt = wave;              // 0..15
    const unsigned short* __restrict__ wlo = wb + WB_ELEMS;
    f32x4 acc = {0.f, 0.f, 0.f, 0.f};
    const int loff = lane * 8;

#pragma unroll 2
    for (int kt = 0; kt < NKT; ++kt) {
        const int base = lds_addr(m16, kt * 32 + oct * 8);
        const float4 a0 = *reinterpret_cast<const float4*>(&lds[base]);
        const float4 a1 = *reinterpret_cast<const float4*>(&lds[base + 4]);
        union U { unsigned u[4]; bf16x8 v; };
        U ah, al;
        ah.u[0] = pack_hi2(a0.x, a0.y); ah.u[1] = pack_hi2(a0.z, a0.w);
        ah.u[2] = pack_hi2(a1.x, a1.y); ah.u[3] = pack_hi2(a1.z, a1.w);
        al.u[0] = pack_hi2(a0.x - hi_part(a0.x), a0.y - hi_part(a0.y));
        al.u[1] = pack_hi2(a0.z - hi_part(a0.z), a0.w - hi_part(a0.w));
        al.u[2] = pack_hi2(a1.x - hi_part(a1.x), a1.y - hi_part(a1.y));
        al.u[3] = pack_hi2(a1.z - hi_part(a1.z), a1.w - hi_part(a1.w));

        const int fb = (kt * 16 + nt) * 512 + loff;
        const bf16x8 wh = *reinterpret_cast<const bf16x8*>(&wb[fb]);
        const bf16x8 wl = *reinterpret_cast<const bf16x8*>(&wlo[fb]);
        acc = __builtin_amdgcn_mfma_f32_16x16x32_bf16(ah.v, wh, acc, 0, 0, 0);
        acc = __builtin_amdgcn_mfma_f32_16x16x32_bf16(al.v, wh, acc, 0, 0, 0);
        acc = __builtin_amdgcn_mfma_f32_16x16x32_bf16(ah.v, wl, acc, 0, 0, 0);
    }

    // D layout: col = lane&15, row = (lane>>4)*4 + reg
    const int colo = nt * 16 + m16;
    const float bs = bias[colo];
#pragma unroll
    for (int j = 0; j < 4; ++j) {
        const int mr = oct * 4 + j;
        const float v = acc[j] + bs;
        const size_t o = (mr < ROWS)
            ? ((size_t)(row0 + mr) * C + colo)
            : ((size_t)NN * C + (size_t)(row0 + mr - ROWS) * C + colo);
        out[o] = v;
    }
}

// ---------------- launch ----------------

extern "C" void kernel_launch(void* const* d_in, const int* in_sizes, int n_in,
                              void* d_out, int out_size, void* d_ws, size_t ws_size,
                              hipStream_t stream) {
    const float* Xr   = (const float*)d_in[0];
    const float* Xi   = (const float*)d_in[1];
    const float* Lr   = (const float*)d_in[2];
    const float* Li   = (const float*)d_in[3];
    const float* W    = (const float*)d_in[4];
    const float* bias = (const float*)d_in[5];
    const int*   rows = (const int*)d_in[6];
    const int*   cols = (const int*)d_in[7];
    float* out = (float*)d_out;

    char* wsb = (char*)d_ws;
    int* cnt     = (int*)wsb;
    int* row_ptr = (int*)(wsb + RP_OFF);
    int* cursor  = (int*)(wsb + CUR_OFF);
    float4* ed   = (float4*)(wsb + ED_OFF);
    unsigned short* wbp = (unsigned short*)(wsb + WB_OFF);
    unsigned* xp = (unsigned*)(wsb + XP_OFF);

    hipMemsetAsync(cnt, 0, NN * sizeof(int), stream);
    k_hist<<<NE / 256, 256, 0, stream>>>(rows, cnt);
    k_scan<<<1, 1024, 0, stream>>>(cnt, row_ptr, cursor);
    k_fill<<<NE / 256, 256, 0, stream>>>(rows, cols, Lr, Li, cursor, ed);
    k_wconv<<<(WB_ELEMS + 255) / 256, 256, 0, stream>>>(W, wbp);
    k_xconv<<<(NN * C) / 256, 256, 0, stream>>>(Xr, Xi, xp);
    k_main<<<NN / ROWS, 1024, 0, stream>>>(xp, ed, wbp, bias, row_ptr, out);
}